// Round 7
// baseline (244.868 us; speedup 1.0000x reference)
//
#include <hip/hip_runtime.h>

// ---------------------------------------------------------------------------
// CapsNet dynamic routing, fully fused, fp32.
//   x: [B=64, I=8192, N=8]   W: [I=8192, J=8, N=8, M=16]   out: [B, J=8, M=16]
//
// b_logits after t iters = dot(sum_{t'<=t} v_{t'}, u_hat); carry only
// vsum[B,J,M] between passes, recompute u_hat per pass (x,W are L3-resident).
//
// Round-6 lesson: 512-thread blocks w/ __launch_bounds__(512,1) = VGPR 120,
// zero spill — but 1 block/CU (2 waves/SIMD) is latency-bound: pass 57 us with
// VALUBusy 25%, DS+VALU floors both ~10 us. Round 7 attacks latency coverage:
//   (a) grid 512 blocks (ICHUNK=16) -> 2 blocks/CU = 4 waves/SIMD
//       (VGPR 120<=128 and LDS 52KBx2=104KB<=160KB both allow it).
//       Partial buffer 16.8 MB, guarded by ws_size with 256-block fallback.
//   (b) x staged in LDS per stage (16KB, coalesced load, stride-68 pad ->
//       the 2-address broadcast reads hit disjoint bank quads, 0 conflict).
//       Inner loop now reads ONLY LDS -> no vmcnt stalls; W fragments
//       (shared across k) hoist to 8 ds_read_b128 per ii.
//
// 1024-thread blocks are hard-capped at 64 VGPR by this toolchain (rounds
// 3-5: waves_per_eu, LDS padding, (1024,1) all failed -> 100 MB spill). Do
// not reintroduce. Keep (512,1).
//
// Thread = (bq, j, mq): owns b in {bq,bq+16,bq+32,bq+48}; one W ds_read_b128
// feeds 4b x 4m = 16 FMAs. WJ_STRIDE=136 -> W reads exact 2-way (free).
// Softmax: m-dot via DPP quad_perm xor1/xor2 (VALU), j-denominator via DPP
// row_ror:4/8 + one shfl_xor(16). No max-subtract (|logit| <~ 1).
// Reduce: coalesced NP-partial sum + squash; first call writes vsum.
// ---------------------------------------------------------------------------

#define BB      64
#define ICAPS   8192
#define NDIM    8
#define JCAPS   8
#define MDIM    16
#define IG      8                     // i's staged per barrier
#define WJ_STRIDE 136                 // 136 mod 32 = 8 -> j-rows 8 banks apart
#define WI_STRIDE (JCAPS * WJ_STRIDE) // 1088 floats per i
#define XB_STRIDE 68                  // x row stride: 68 mod 32 = 4 -> the two
                                      // in-wave b-addresses hit disjoint quads
#define S_ELEMS  (BB * JCAPS * MDIM)  // 8192 floats per s / vsum / out

// butterfly / rotate adds on the VALU pipe via DPP.
template <int CTRL>
__device__ __forceinline__ float dpp_xadd(float v) {
    const int p = __builtin_amdgcn_mov_dpp(__float_as_int(v), CTRL, 0xF, 0xF, true);
    return v + __int_as_float(p);
}
#define DPP_XOR1 0xB1   // quad_perm [1,0,3,2]
#define DPP_XOR2 0x4E   // quad_perm [2,3,0,1]
#define DPP_ROR4 0x124  // row_ror:4
#define DPP_ROR8 0x128  // row_ror:8

// MODE 0: uniform c = 1/8 (softmax of zero logits)
// MODE 1: c = softmax_j( dot(vsum[b,j,:], u_hat[b,i,j,:]) )
// NCH: i's per block (16 for the 512-block path, 32 for the fallback)
template <int MODE, int NCH>
__global__ __launch_bounds__(512, 1)
void caps_pass_kernel(
    const float* __restrict__ x, const float* __restrict__ W,
    const float* __restrict__ vsum, float* __restrict__ partial)
{
    __shared__ float Wlds[IG * WI_STRIDE];   // 34,816 B
    __shared__ float Xlds[BB * XB_STRIDE];   // 17,408 B  (52,224 total)

    const int tid = threadIdx.x;             // 0..511
    const int mq  = tid & 3;                 // m-quad (lane bits 0-1)
    const int j   = (tid >> 2) & 7;          // out-cap (lane bits 2-4)
    const int bq  = tid >> 5;                // 0..15 batch-quad base
    const int blk = blockIdx.x;
    const int i0  = blk * NCH;

    float s[4][4];                           // [b-quad][m-quad]
    #pragma unroll
    for (int k = 0; k < 4; ++k)
        #pragma unroll
        for (int m = 0; m < 4; ++m) s[k][m] = 0.f;

    float v[4][4];
    if (MODE == 1) {
        #pragma unroll
        for (int k = 0; k < 4; ++k) {
            const float4 a = *(const float4*)
                &vsum[((bq + 16 * k) * JCAPS + j) * MDIM + mq * 4];
            v[k][0] = a.x; v[k][1] = a.y; v[k][2] = a.z; v[k][3] = a.w;
        }
    }

    for (int st = 0; st < NCH / IG; ++st) {
        // ---- stage W for IG i's (each thread: 16 contiguous floats) ----
        {
            const int iL  = tid >> 6;        // 0..7
            const int rem = tid & 63;        // 16-float chunk within the i
            const float4* src = (const float4*)(W + (size_t)(i0 + st * IG + iL) * 1024
                                                  + rem * 16);
            float4* dst = (float4*)&Wlds[iL * WI_STRIDE + (rem >> 3) * WJ_STRIDE
                                         + (rem & 7) * 16];
            dst[0] = src[0]; dst[1] = src[1]; dst[2] = src[2]; dst[3] = src[3];
        }
        // ---- stage x for IG i's, all 64 b (each thread: 8 floats = one i) ----
        {
            const int tb = tid >> 3;         // 0..63 batch
            const int tn = tid & 7;          // which i of the stage
            const float4* src = (const float4*)(x + ((size_t)tb * ICAPS + i0 + st * IG)
                                                      * NDIM + tn * 8);
            float4* dst = (float4*)&Xlds[tb * XB_STRIDE + tn * 8];
            dst[0] = src[0]; dst[1] = src[1];
        }
        __syncthreads();

        #pragma unroll
        for (int ii = 0; ii < IG; ++ii) {
            // W fragment: shared across the 4 b's -> hoist all 8 n-quads
            const float* wb = &Wlds[ii * WI_STRIDE + j * WJ_STRIDE + mq * 4];
            float4 w0 = *(const float4*)&wb[0 * MDIM];
            float4 w1 = *(const float4*)&wb[1 * MDIM];
            float4 w2 = *(const float4*)&wb[2 * MDIM];
            float4 w3 = *(const float4*)&wb[3 * MDIM];
            float4 w4 = *(const float4*)&wb[4 * MDIM];
            float4 w5 = *(const float4*)&wb[5 * MDIM];
            float4 w6 = *(const float4*)&wb[6 * MDIM];
            float4 w7 = *(const float4*)&wb[7 * MDIM];

            float u[4][4];
            #pragma unroll
            for (int k = 0; k < 4; ++k) {
                const float* xp = &Xlds[(bq + 16 * k) * XB_STRIDE + ii * 8];
                const float4 xA = *(const float4*)xp;        // n = 0..3 (broadcast)
                const float4 xB = *(const float4*)(xp + 4);  // n = 4..7
                u[k][0]  = xA.x * w0.x; u[k][1]  = xA.x * w0.y;
                u[k][2]  = xA.x * w0.z; u[k][3]  = xA.x * w0.w;
                u[k][0] += xA.y * w1.x; u[k][1] += xA.y * w1.y;
                u[k][2] += xA.y * w1.z; u[k][3] += xA.y * w1.w;
                u[k][0] += xA.z * w2.x; u[k][1] += xA.z * w2.y;
                u[k][2] += xA.z * w2.z; u[k][3] += xA.z * w2.w;
                u[k][0] += xA.w * w3.x; u[k][1] += xA.w * w3.y;
                u[k][2] += xA.w * w3.z; u[k][3] += xA.w * w3.w;
                u[k][0] += xB.x * w4.x; u[k][1] += xB.x * w4.y;
                u[k][2] += xB.x * w4.z; u[k][3] += xB.x * w4.w;
                u[k][0] += xB.y * w5.x; u[k][1] += xB.y * w5.y;
                u[k][2] += xB.y * w5.z; u[k][3] += xB.y * w5.w;
                u[k][0] += xB.z * w6.x; u[k][1] += xB.z * w6.y;
                u[k][2] += xB.z * w6.z; u[k][3] += xB.z * w6.w;
                u[k][0] += xB.w * w7.x; u[k][1] += xB.w * w7.y;
                u[k][2] += xB.w * w7.z; u[k][3] += xB.w * w7.w;
            }

            if (MODE == 0) {
                #pragma unroll
                for (int k = 0; k < 4; ++k)
                    #pragma unroll
                    for (int m = 0; m < 4; ++m) s[k][m] += u[k][m];
            } else {
                // partial logit over this m-quad (4 independent chains)
                float lp[4];
                #pragma unroll
                for (int k = 0; k < 4; ++k)
                    lp[k] = u[k][0] * v[k][0] + u[k][1] * v[k][1]
                          + u[k][2] * v[k][2] + u[k][3] * v[k][3];
                // complete m-dot across the 4 mq lanes: DPP quad_perm (VALU)
                #pragma unroll
                for (int k = 0; k < 4; ++k) lp[k] = dpp_xadd<DPP_XOR1>(lp[k]);
                #pragma unroll
                for (int k = 0; k < 4; ++k) lp[k] = dpp_xadd<DPP_XOR2>(lp[k]);
                // softmax over 8 j's: quads uniform -> row_ror:4/8 (VALU) sums
                // the 4 j's of this 16-row; one shfl_xor(16) folds the other.
                float e[4], d[4];
                #pragma unroll
                for (int k = 0; k < 4; ++k) { e[k] = __expf(lp[k]); }
                #pragma unroll
                for (int k = 0; k < 4; ++k) d[k] = dpp_xadd<DPP_ROR4>(e[k]);
                #pragma unroll
                for (int k = 0; k < 4; ++k) d[k] = dpp_xadd<DPP_ROR8>(d[k]);
                #pragma unroll
                for (int k = 0; k < 4; ++k) d[k] += __shfl_xor(d[k], 16);
                #pragma unroll
                for (int k = 0; k < 4; ++k) {
                    const float c = e[k] * __builtin_amdgcn_rcpf(d[k]);
                    #pragma unroll
                    for (int m = 0; m < 4; ++m) s[k][m] += c * u[k][m];
                }
            }
        }
        __syncthreads();
    }

    // ---- store block-partial s: partial[blk][b][j][m] (each owned once) ----
    const float sc = (MODE == 0) ? 0.125f : 1.0f;
    float* pp = partial + (size_t)blk * S_ELEMS;
    #pragma unroll
    for (int k = 0; k < 4; ++k) {
        float4 o;
        o.x = s[k][0] * sc; o.y = s[k][1] * sc;
        o.z = s[k][2] * sc; o.w = s[k][3] * sc;
        *(float4*)&pp[((bq + 16 * k) * JCAPS + j) * MDIM + mq * 4] = o;
    }
}

// Sum npg*4 partials -> s[b,j,m]; v = squash(s).
// OP 0: vsum = v (first pass, avoids memset)   OP 1: vsum += v   OP 2: out = v
template <int OP>
__global__ __launch_bounds__(256) void caps_reduce_kernel(
    const float* __restrict__ partial, float* __restrict__ vsum,
    float* __restrict__ out, int npg)
{
    __shared__ float sd[256];
    const int bo  = blockIdx.x;     // 0..127, each block covers 64 outputs
    const int tid = threadIdx.x;
    const int kg  = tid >> 6;       // 0..3  partial-group (npg partials each)
    const int tl  = tid & 63;       // output-within-block; lanes contiguous in t
    const int t   = bo * 64 + tl;   // global output index (= b*128 + j*16 + m)

    float a0 = 0.f, a1 = 0.f, a2 = 0.f, a3 = 0.f;
    const float* p = partial + (size_t)kg * npg * S_ELEMS + t;
    for (int k = 0; k < npg; k += 4) {
        a0 += p[(size_t)(k + 0) * S_ELEMS];
        a1 += p[(size_t)(k + 1) * S_ELEMS];
        a2 += p[(size_t)(k + 2) * S_ELEMS];
        a3 += p[(size_t)(k + 3) * S_ELEMS];
    }
    sd[tid] = (a0 + a1) + (a2 + a3);
    __syncthreads();

    if (tid < 64) {
        const float s = (sd[tid] + sd[64 + tid]) + (sd[128 + tid] + sd[192 + tid]);
        // squash: sn over the 16 m's of this (b,j) — lanes grouped by 16
        float sn = s * s;
        sn += __shfl_xor(sn, 1);
        sn += __shfl_xor(sn, 2);
        sn += __shfl_xor(sn, 4);
        sn += __shfl_xor(sn, 8);
        const float v = s * sqrtf(sn) / (1.f + sn);
        const int tt = bo * 64 + tid;
        if (OP == 2)      out[tt]   = v;
        else if (OP == 1) vsum[tt] += v;
        else              vsum[tt]  = v;
    }
}

extern "C" void kernel_launch(void* const* d_in, const int* in_sizes, int n_in,
                              void* d_out, int out_size, void* d_ws, size_t ws_size,
                              hipStream_t stream)
{
    const float* x = (const float*)d_in[0];   // [64, 8192, 8]
    const float* W = (const float*)d_in[1];   // [8192, 8, 8, 16]
    float* out = (float*)d_out;               // [64, 8, 16]

    // 512-block path needs (512+1)*8192 floats = 16.8 MB of workspace.
    const bool big = ws_size >= (size_t)(512 + 1) * S_ELEMS * sizeof(float);
    const int NP   = big ? 512 : 256;
    const int npg  = NP / 4;

    float* partial = (float*)d_ws;                       // NP * 8192 floats
    float* vsum    = partial + (size_t)NP * S_ELEMS;     // 8192 floats

    if (big) {
        caps_pass_kernel<0, 16><<<512, 512, 0, stream>>>(x, W, vsum, partial);
        caps_reduce_kernel<0><<<128, 256, 0, stream>>>(partial, vsum, nullptr, npg);
        caps_pass_kernel<1, 16><<<512, 512, 0, stream>>>(x, W, vsum, partial);
        caps_reduce_kernel<1><<<128, 256, 0, stream>>>(partial, vsum, nullptr, npg);
        caps_pass_kernel<1, 16><<<512, 512, 0, stream>>>(x, W, vsum, partial);
        caps_reduce_kernel<2><<<128, 256, 0, stream>>>(partial, vsum, out, npg);
    } else {
        caps_pass_kernel<0, 32><<<256, 512, 0, stream>>>(x, W, vsum, partial);
        caps_reduce_kernel<0><<<128, 256, 0, stream>>>(partial, vsum, nullptr, npg);
        caps_pass_kernel<1, 32><<<256, 512, 0, stream>>>(x, W, vsum, partial);
        caps_reduce_kernel<1><<<128, 256, 0, stream>>>(partial, vsum, nullptr, npg);
        caps_pass_kernel<1, 32><<<256, 512, 0, stream>>>(x, W, vsum, partial);
        caps_reduce_kernel<2><<<128, 256, 0, stream>>>(partial, vsum, out, npg);
    }
}

// Round 8
// 237.010 us; speedup vs baseline: 1.0332x; 1.0332x over previous
//
#include <hip/hip_runtime.h>

// ---------------------------------------------------------------------------
// CapsNet dynamic routing, fully fused, fp32.
//   x: [B=64, I=8192, N=8]   W: [I=8192, J=8, N=8, M=16]   out: [B, J=8, M=16]
//
// b_logits after t iters = dot(sum_{t'<=t} v_{t'}, u_hat); carry only
// vsum[B,J,M] between passes, recompute u_hat per pass (x,W are L3-resident).
//
// Round-8 synthesis of two HW-verified facts:
//   * Round 6 register STRUCTURE (n-split halves, inline wq reads, xa[4])
//     compiles to VGPR=120 with ZERO spill at __launch_bounds__(512,1).
//   * Round 7 showed hoisting w0..w7 (32 regs) pushes past the budget ->
//     VGPR=128 -> ~53 MB/pass scratch spill AND kills 2-block co-residency
//     (4 waves/SIMD x 128 = whole file; occupancy stayed 18%).
// So: round-6 inner loop verbatim, x source switched global->LDS (bases are
// per-thread constants; ii/n are compile-time ds_read offsets), grid 512
// (2 blocks/CU; LDS 52,224 B x 2 = 104 KB <= 160 KB). Target VGPR <= 120.
//
// 1024-thread blocks are hard-capped at 64 VGPR by this toolchain (rounds
// 3-5: waves_per_eu, LDS padding, (1024,1) all failed -> 100 MB spill). Do
// not reintroduce. Keep (512,1).
//
// Thread = (bq, j, mq): owns b in {bq,bq+16,bq+32,bq+48}; one W ds_read_b128
// feeds 4b x 4m = 16 FMAs. WJ_STRIDE=136 -> W reads 2-way bank overlap (free).
// XB_STRIDE=68 -> x broadcast reads (2 distinct addrs/wave) conflict-benign.
// Softmax: m-dot via DPP quad_perm xor1/xor2 (VALU), j-denominator via DPP
// row_ror:4/8 + one shfl_xor(16). No max-subtract (|logit| <~ 1).
// Reduce: 256 blocks x 256 thr, 8 groups x 4-ILP (round-7's 128x256 deep
// chain cost ~89 us across the bench); first call writes vsum (no memset).
// ---------------------------------------------------------------------------

#define BB      64
#define ICAPS   8192
#define NDIM    8
#define JCAPS   8
#define MDIM    16
#define IG      8                     // i's staged per barrier
#define WJ_STRIDE 136                 // 136 mod 32 = 8 -> j-rows 8 banks apart
#define WI_STRIDE (JCAPS * WJ_STRIDE) // 1088 floats per i
#define XB_STRIDE 68                  // x row stride: 68 mod 32 = 4
#define S_ELEMS  (BB * JCAPS * MDIM)  // 8192 floats per s / vsum / out

// butterfly / rotate adds on the VALU pipe via DPP.
template <int CTRL>
__device__ __forceinline__ float dpp_xadd(float v) {
    const int p = __builtin_amdgcn_mov_dpp(__float_as_int(v), CTRL, 0xF, 0xF, true);
    return v + __int_as_float(p);
}
#define DPP_XOR1 0xB1   // quad_perm [1,0,3,2]
#define DPP_XOR2 0x4E   // quad_perm [2,3,0,1]
#define DPP_ROR4 0x124  // row_ror:4
#define DPP_ROR8 0x128  // row_ror:8

// MODE 0: uniform c = 1/8 (softmax of zero logits)
// MODE 1: c = softmax_j( dot(vsum[b,j,:], u_hat[b,i,j,:]) )
// NCH: i's per block (16 for the 512-block path, 32 for the fallback)
template <int MODE, int NCH>
__global__ __launch_bounds__(512, 1)
void caps_pass_kernel(
    const float* __restrict__ x, const float* __restrict__ W,
    const float* __restrict__ vsum, float* __restrict__ partial)
{
    __shared__ float Wlds[IG * WI_STRIDE];   // 34,816 B
    __shared__ float Xlds[BB * XB_STRIDE];   // 17,408 B  (52,224 total)

    const int tid = threadIdx.x;             // 0..511
    const int mq  = tid & 3;                 // m-quad (lane bits 0-1)
    const int j   = (tid >> 2) & 7;          // out-cap (lane bits 2-4)
    const int bq  = tid >> 5;                // 0..15 batch-quad base
    const int blk = blockIdx.x;
    const int i0  = blk * NCH;

    float s[4][4];                           // [b-quad][m-quad]
    #pragma unroll
    for (int k = 0; k < 4; ++k)
        #pragma unroll
        for (int m = 0; m < 4; ++m) s[k][m] = 0.f;

    float v[4][4];
    if (MODE == 1) {
        #pragma unroll
        for (int k = 0; k < 4; ++k) {
            const float4 a = *(const float4*)
                &vsum[((bq + 16 * k) * JCAPS + j) * MDIM + mq * 4];
            v[k][0] = a.x; v[k][1] = a.y; v[k][2] = a.z; v[k][3] = a.w;
        }
    }

    // per-thread constant LDS bases (compile-time offsets do the rest)
    const float* wjb = &Wlds[j * WJ_STRIDE + mq * 4];
    const float* xb0 = &Xlds[(bq +  0) * XB_STRIDE];
    const float* xb1 = &Xlds[(bq + 16) * XB_STRIDE];
    const float* xb2 = &Xlds[(bq + 32) * XB_STRIDE];
    const float* xb3 = &Xlds[(bq + 48) * XB_STRIDE];

    for (int st = 0; st < NCH / IG; ++st) {
        // ---- stage W for IG i's (each thread: 16 contiguous floats) ----
        {
            const int iL  = tid >> 6;        // 0..7
            const int rem = tid & 63;        // 16-float chunk within the i
            const float4* src = (const float4*)(W + (size_t)(i0 + st * IG + iL) * 1024
                                                  + rem * 16);
            float4* dst = (float4*)&Wlds[iL * WI_STRIDE + (rem >> 3) * WJ_STRIDE
                                         + (rem & 7) * 16];
            dst[0] = src[0]; dst[1] = src[1]; dst[2] = src[2]; dst[3] = src[3];
        }
        // ---- stage x for IG i's, all 64 b (each thread: 8 floats = one i) ----
        {
            const int tb = tid >> 3;         // 0..63 batch
            const int tn = tid & 7;          // which i of the stage
            const float4* src = (const float4*)(x + ((size_t)tb * ICAPS + i0 + st * IG)
                                                      * NDIM + tn * 8);
            float4* dst = (float4*)&Xlds[tb * XB_STRIDE + tn * 8];
            dst[0] = src[0]; dst[1] = src[1];
        }
        __syncthreads();

        #pragma unroll
        for (int ii = 0; ii < IG; ++ii) {
            const float* wb = wjb + ii * WI_STRIDE;

            float u[4][4];
            #pragma unroll
            for (int k = 0; k < 4; ++k)
                #pragma unroll
                for (int m = 0; m < 4; ++m) u[k][m] = 0.f;

            // n-split halves (round-6 structure: keeps live state ~80 floats)
            {   // n = 0..3
                float4 xa[4];
                xa[0] = *(const float4*)(xb0 + ii * 8);
                xa[1] = *(const float4*)(xb1 + ii * 8);
                xa[2] = *(const float4*)(xb2 + ii * 8);
                xa[3] = *(const float4*)(xb3 + ii * 8);
                #pragma unroll
                for (int n = 0; n < 4; ++n) {
                    const float4 wq = *(const float4*)&wb[n * MDIM];
                    #pragma unroll
                    for (int k = 0; k < 4; ++k) {
                        const float xn = (n == 0) ? xa[k].x : (n == 1) ? xa[k].y
                                       : (n == 2) ? xa[k].z : xa[k].w;
                        u[k][0] += xn * wq.x; u[k][1] += xn * wq.y;
                        u[k][2] += xn * wq.z; u[k][3] += xn * wq.w;
                    }
                }
            }
            {   // n = 4..7
                float4 xb[4];
                xb[0] = *(const float4*)(xb0 + ii * 8 + 4);
                xb[1] = *(const float4*)(xb1 + ii * 8 + 4);
                xb[2] = *(const float4*)(xb2 + ii * 8 + 4);
                xb[3] = *(const float4*)(xb3 + ii * 8 + 4);
                #pragma unroll
                for (int n = 0; n < 4; ++n) {
                    const float4 wq = *(const float4*)&wb[(n + 4) * MDIM];
                    #pragma unroll
                    for (int k = 0; k < 4; ++k) {
                        const float xn = (n == 0) ? xb[k].x : (n == 1) ? xb[k].y
                                       : (n == 2) ? xb[k].z : xb[k].w;
                        u[k][0] += xn * wq.x; u[k][1] += xn * wq.y;
                        u[k][2] += xn * wq.z; u[k][3] += xn * wq.w;
                    }
                }
            }

            if (MODE == 0) {
                #pragma unroll
                for (int k = 0; k < 4; ++k)
                    #pragma unroll
                    for (int m = 0; m < 4; ++m) s[k][m] += u[k][m];
            } else {
                // partial logit over this m-quad (4 independent chains)
                float lp[4];
                #pragma unroll
                for (int k = 0; k < 4; ++k)
                    lp[k] = u[k][0] * v[k][0] + u[k][1] * v[k][1]
                          + u[k][2] * v[k][2] + u[k][3] * v[k][3];
                // complete m-dot across the 4 mq lanes: DPP quad_perm (VALU)
                #pragma unroll
                for (int k = 0; k < 4; ++k) lp[k] = dpp_xadd<DPP_XOR1>(lp[k]);
                #pragma unroll
                for (int k = 0; k < 4; ++k) lp[k] = dpp_xadd<DPP_XOR2>(lp[k]);
                // softmax over 8 j's: quads uniform -> row_ror:4/8 (VALU) sums
                // the 4 j's of this 16-row; one shfl_xor(16) folds the other.
                float e[4], d[4];
                #pragma unroll
                for (int k = 0; k < 4; ++k) { e[k] = __expf(lp[k]); }
                #pragma unroll
                for (int k = 0; k < 4; ++k) d[k] = dpp_xadd<DPP_ROR4>(e[k]);
                #pragma unroll
                for (int k = 0; k < 4; ++k) d[k] = dpp_xadd<DPP_ROR8>(d[k]);
                #pragma unroll
                for (int k = 0; k < 4; ++k) d[k] += __shfl_xor(d[k], 16);
                #pragma unroll
                for (int k = 0; k < 4; ++k) {
                    const float c = e[k] * __builtin_amdgcn_rcpf(d[k]);
                    #pragma unroll
                    for (int m = 0; m < 4; ++m) s[k][m] += c * u[k][m];
                }
            }
        }
        __syncthreads();
    }

    // ---- store block-partial s: partial[blk][b][j][m] (each owned once) ----
    const float sc = (MODE == 0) ? 0.125f : 1.0f;
    float* pp = partial + (size_t)blk * S_ELEMS;
    #pragma unroll
    for (int k = 0; k < 4; ++k) {
        float4 o;
        o.x = s[k][0] * sc; o.y = s[k][1] * sc;
        o.z = s[k][2] * sc; o.w = s[k][3] * sc;
        *(float4*)&pp[((bq + 16 * k) * JCAPS + j) * MDIM + mq * 4] = o;
    }
}

// Sum NP partials -> s[b,j,m]; v = squash(s). 256 blocks x 256 threads:
// 8 partial-groups of npg = NP/8 each, 4-way ILP inside a group.
// OP 0: vsum = v (first pass, avoids memset)   OP 1: vsum += v   OP 2: out = v
template <int OP>
__global__ __launch_bounds__(256) void caps_reduce_kernel(
    const float* __restrict__ partial, float* __restrict__ vsum,
    float* __restrict__ out, int npg)
{
    __shared__ float sd[256];
    const int bo  = blockIdx.x;     // 0..255, each block covers 32 outputs
    const int tid = threadIdx.x;
    const int kg  = tid >> 5;       // 0..7  partial-group
    const int tl  = tid & 31;       // output-within-block; lanes contiguous in t
    const int t   = bo * 32 + tl;   // global output index (= b*128 + j*16 + m)

    float a0 = 0.f, a1 = 0.f, a2 = 0.f, a3 = 0.f;
    const float* p = partial + (size_t)kg * npg * S_ELEMS + t;
    for (int k = 0; k < npg; k += 4) {
        a0 += p[(size_t)(k + 0) * S_ELEMS];
        a1 += p[(size_t)(k + 1) * S_ELEMS];
        a2 += p[(size_t)(k + 2) * S_ELEMS];
        a3 += p[(size_t)(k + 3) * S_ELEMS];
    }
    sd[tid] = (a0 + a1) + (a2 + a3);
    __syncthreads();

    if (tid < 32) {
        float s = 0.f;
        #pragma unroll
        for (int q = 0; q < 8; ++q) s += sd[q * 32 + tid];
        // squash: sn over the 16 m's of this (b,j) — lanes grouped by 16
        float sn = s * s;
        sn += __shfl_xor(sn, 1);
        sn += __shfl_xor(sn, 2);
        sn += __shfl_xor(sn, 4);
        sn += __shfl_xor(sn, 8);
        const float v = s * sqrtf(sn) / (1.f + sn);
        const int tt = bo * 32 + tid;
        if (OP == 2)      out[tt]   = v;
        else if (OP == 1) vsum[tt] += v;
        else              vsum[tt]  = v;
    }
}

extern "C" void kernel_launch(void* const* d_in, const int* in_sizes, int n_in,
                              void* d_out, int out_size, void* d_ws, size_t ws_size,
                              hipStream_t stream)
{
    const float* x = (const float*)d_in[0];   // [64, 8192, 8]
    const float* W = (const float*)d_in[1];   // [8192, 8, 8, 16]
    float* out = (float*)d_out;               // [64, 8, 16]

    // 512-block path needs (512+1)*8192 floats = 16.8 MB of workspace.
    const bool big = ws_size >= (size_t)(512 + 1) * S_ELEMS * sizeof(float);
    const int NP   = big ? 512 : 256;
    const int npg  = NP / 8;

    float* partial = (float*)d_ws;                       // NP * 8192 floats
    float* vsum    = partial + (size_t)NP * S_ELEMS;     // 8192 floats

    if (big) {
        caps_pass_kernel<0, 16><<<512, 512, 0, stream>>>(x, W, vsum, partial);
        caps_reduce_kernel<0><<<256, 256, 0, stream>>>(partial, vsum, nullptr, npg);
        caps_pass_kernel<1, 16><<<512, 512, 0, stream>>>(x, W, vsum, partial);
        caps_reduce_kernel<1><<<256, 256, 0, stream>>>(partial, vsum, nullptr, npg);
        caps_pass_kernel<1, 16><<<512, 512, 0, stream>>>(x, W, vsum, partial);
        caps_reduce_kernel<2><<<256, 256, 0, stream>>>(partial, vsum, out, npg);
    } else {
        caps_pass_kernel<0, 32><<<256, 512, 0, stream>>>(x, W, vsum, partial);
        caps_reduce_kernel<0><<<256, 256, 0, stream>>>(partial, vsum, nullptr, npg);
        caps_pass_kernel<1, 32><<<256, 512, 0, stream>>>(x, W, vsum, partial);
        caps_reduce_kernel<1><<<256, 256, 0, stream>>>(partial, vsum, nullptr, npg);
        caps_pass_kernel<1, 32><<<256, 512, 0, stream>>>(x, W, vsum, partial);
        caps_reduce_kernel<2><<<256, 256, 0, stream>>>(partial, vsum, out, npg);
    }
}

// Round 9
// 195.893 us; speedup vs baseline: 1.2500x; 1.2099x over previous
//
#include <hip/hip_runtime.h>

// ---------------------------------------------------------------------------
// CapsNet dynamic routing, fully fused, fp32.
//   x: [B=64, I=8192, N=8]   W: [I=8192, J=8, N=8, M=16]   out: [B, J=8, M=16]
//
// b_logits after t iters = dot(sum_{t'<=t} v_{t'}, u_hat); carry only
// vsum[B,J,M] between passes, recompute u_hat per pass (x,W are L3-resident).
//
// Round-9 = the two HW-proven pieces, finally combined, nothing new:
//   * Pass body = round 6 VERBATIM (x from GLOBAL, n-split halves, DPP
//     softmax): measured VGPR=120, ZERO scratch at __launch_bounds__(512,1).
//     x-in-LDS variants (rounds 7+8, two formulations) both hit VGPR=128 +
//     ~53 MB/pass scratch spill -> and the per-wave scratch allocation is
//     what BLOCKED 2-block co-residency (occupancy stuck 18%). Do not stage
//     x in LDS again.
//   * Grid 512, NCH=16: VGPR 120 <= 128 and LDS 34.8KBx2 = 69.6 <= 160KB ->
//     2 blocks/CU = 16 waves/CU, 2x the latency hiding that capped round 6
//     at 57 us (both pipes <30% busy = stall-bound at 8 waves/CU).
//   * Reduce for NP=512 re-geometried: 256 blocks x 512 thr (8 waves/CU),
//     16 groups x 32 partials x 8-ILP -> serial-chain depth 4. The round-7/8
//     reduce (1 wave-deep occupancy, depth 16) ate ~20 us per call.
// 1024-thread blocks are hard-capped at 64 VGPR (rounds 3-5). Keep (512,1).
//
// Thread = (bq, j, mq): owns b in {bq,bq+16,bq+32,bq+48}; one W ds_read_b128
// feeds 4b x 4m = 16 FMAs. WJ_STRIDE=136 -> W reads 2-way bank overlap (free).
// Softmax: m-dot via DPP quad_perm xor1/xor2 (VALU), j-denominator via DPP
// row_ror:4/8 + one shfl_xor(16). No max-subtract (|logit| <~ 1).
// ---------------------------------------------------------------------------

#define BB      64
#define ICAPS   8192
#define NDIM    8
#define JCAPS   8
#define MDIM    16
#define IG      8                     // i's staged per barrier
#define WJ_STRIDE 136                 // 136 mod 32 = 8 -> j-rows 8 banks apart
#define WI_STRIDE (JCAPS * WJ_STRIDE) // 1088 floats per i
#define S_ELEMS  (BB * JCAPS * MDIM)  // 8192 floats per s / vsum / out

// butterfly / rotate adds on the VALU pipe via DPP.
template <int CTRL>
__device__ __forceinline__ float dpp_xadd(float v) {
    const int p = __builtin_amdgcn_mov_dpp(__float_as_int(v), CTRL, 0xF, 0xF, true);
    return v + __int_as_float(p);
}
#define DPP_XOR1 0xB1   // quad_perm [1,0,3,2]
#define DPP_XOR2 0x4E   // quad_perm [2,3,0,1]
#define DPP_ROR4 0x124  // row_ror:4
#define DPP_ROR8 0x128  // row_ror:8

// MODE 0: uniform c = 1/8 (softmax of zero logits)
// MODE 1: c = softmax_j( dot(vsum[b,j,:], u_hat[b,i,j,:]) )
// NCH: i's per block (16 for the 512-grid path, 32 for the 256 fallback)
template <int MODE, int NCH>
__global__ __launch_bounds__(512, 1)
void caps_pass_kernel(
    const float* __restrict__ x, const float* __restrict__ W,
    const float* __restrict__ vsum, float* __restrict__ partial)
{
    __shared__ float Wlds[IG * WI_STRIDE];   // 34,816 B

    const int tid = threadIdx.x;             // 0..511
    const int mq  = tid & 3;                 // m-quad (lane bits 0-1)
    const int j   = (tid >> 2) & 7;          // out-cap (lane bits 2-4)
    const int bq  = tid >> 5;                // 0..15 batch-quad base
    const int blk = blockIdx.x;
    const int i0  = blk * NCH;

    float s[4][4];                           // [b-quad][m-quad]
    #pragma unroll
    for (int k = 0; k < 4; ++k)
        #pragma unroll
        for (int m = 0; m < 4; ++m) s[k][m] = 0.f;

    float v[4][4];
    if (MODE == 1) {
        #pragma unroll
        for (int k = 0; k < 4; ++k) {
            const float4 a = *(const float4*)
                &vsum[((bq + 16 * k) * JCAPS + j) * MDIM + mq * 4];
            v[k][0] = a.x; v[k][1] = a.y; v[k][2] = a.z; v[k][3] = a.w;
        }
    }

    for (int st = 0; st < NCH / IG; ++st) {
        // ---- stage W for IG i's (each thread: 16 contiguous floats) ----
        {
            const int iL  = tid >> 6;        // 0..7
            const int rem = tid & 63;        // 16-float chunk within the i
            const float4* src = (const float4*)(W + (size_t)(i0 + st * IG + iL) * 1024
                                                  + rem * 16);
            float4* dst = (float4*)&Wlds[iL * WI_STRIDE + (rem >> 3) * WJ_STRIDE
                                         + (rem & 7) * 16];
            dst[0] = src[0]; dst[1] = src[1]; dst[2] = src[2]; dst[3] = src[3];
        }
        __syncthreads();

        #pragma unroll
        for (int ii = 0; ii < IG; ++ii) {
            const int i = i0 + st * IG + ii;

            float u[4][4];
            #pragma unroll
            for (int k = 0; k < 4; ++k)
                #pragma unroll
                for (int m = 0; m < 4; ++m) u[k][m] = 0.f;
            const float* wb = &Wlds[ii * WI_STRIDE + j * WJ_STRIDE + mq * 4];

            // n-split: keep only 16 x-floats live at a time (VGPR pressure)
            {   // n = 0..3
                float4 xa[4];
                #pragma unroll
                for (int k = 0; k < 4; ++k)
                    xa[k] = *(const float4*)&x[((size_t)(bq + 16 * k) * ICAPS + i) * NDIM];
                #pragma unroll
                for (int n = 0; n < 4; ++n) {
                    const float4 wq = *(const float4*)&wb[n * MDIM];
                    #pragma unroll
                    for (int k = 0; k < 4; ++k) {
                        const float xn = (n == 0) ? xa[k].x : (n == 1) ? xa[k].y
                                       : (n == 2) ? xa[k].z : xa[k].w;
                        u[k][0] += xn * wq.x; u[k][1] += xn * wq.y;
                        u[k][2] += xn * wq.z; u[k][3] += xn * wq.w;
                    }
                }
            }
            {   // n = 4..7
                float4 xb[4];
                #pragma unroll
                for (int k = 0; k < 4; ++k)
                    xb[k] = *(const float4*)&x[((size_t)(bq + 16 * k) * ICAPS + i) * NDIM + 4];
                #pragma unroll
                for (int n = 0; n < 4; ++n) {
                    const float4 wq = *(const float4*)&wb[(n + 4) * MDIM];
                    #pragma unroll
                    for (int k = 0; k < 4; ++k) {
                        const float xn = (n == 0) ? xb[k].x : (n == 1) ? xb[k].y
                                       : (n == 2) ? xb[k].z : xb[k].w;
                        u[k][0] += xn * wq.x; u[k][1] += xn * wq.y;
                        u[k][2] += xn * wq.z; u[k][3] += xn * wq.w;
                    }
                }
            }

            if (MODE == 0) {
                #pragma unroll
                for (int k = 0; k < 4; ++k)
                    #pragma unroll
                    for (int m = 0; m < 4; ++m) s[k][m] += u[k][m];
            } else {
                // partial logit over this m-quad (4 independent chains)
                float lp[4];
                #pragma unroll
                for (int k = 0; k < 4; ++k)
                    lp[k] = u[k][0] * v[k][0] + u[k][1] * v[k][1]
                          + u[k][2] * v[k][2] + u[k][3] * v[k][3];
                // complete m-dot across the 4 mq lanes: DPP quad_perm (VALU)
                #pragma unroll
                for (int k = 0; k < 4; ++k) lp[k] = dpp_xadd<DPP_XOR1>(lp[k]);
                #pragma unroll
                for (int k = 0; k < 4; ++k) lp[k] = dpp_xadd<DPP_XOR2>(lp[k]);
                // softmax over 8 j's: quads uniform -> row_ror:4/8 (VALU) sums
                // the 4 j's of this 16-row; one shfl_xor(16) folds the other.
                float e[4], d[4];
                #pragma unroll
                for (int k = 0; k < 4; ++k) { e[k] = __expf(lp[k]); }
                #pragma unroll
                for (int k = 0; k < 4; ++k) d[k] = dpp_xadd<DPP_ROR4>(e[k]);
                #pragma unroll
                for (int k = 0; k < 4; ++k) d[k] = dpp_xadd<DPP_ROR8>(d[k]);
                #pragma unroll
                for (int k = 0; k < 4; ++k) d[k] += __shfl_xor(d[k], 16);
                #pragma unroll
                for (int k = 0; k < 4; ++k) {
                    const float c = e[k] * __builtin_amdgcn_rcpf(d[k]);
                    #pragma unroll
                    for (int m = 0; m < 4; ++m) s[k][m] += c * u[k][m];
                }
            }
        }
        __syncthreads();
    }

    // ---- store block-partial s: partial[blk][b][j][m] (each owned once) ----
    const float sc = (MODE == 0) ? 0.125f : 1.0f;
    float* pp = partial + (size_t)blk * S_ELEMS;
    #pragma unroll
    for (int k = 0; k < 4; ++k) {
        float4 o;
        o.x = s[k][0] * sc; o.y = s[k][1] * sc;
        o.z = s[k][2] * sc; o.w = s[k][3] * sc;
        *(float4*)&pp[((bq + 16 * k) * JCAPS + j) * MDIM + mq * 4] = o;
    }
}

// Sum NPART partials -> s[b,j,m]; v = squash(s). 256 blocks x 512 threads
// (8 waves/CU): 16 groups of NPART/16 partials, 8-way ILP -> serial chain
// depth NPART/128. Round-7/8 geometry (1 wave/SIMD, depth 16) cost ~20 us.
// OP 0: vsum = v (first pass, avoids memset)   OP 1: vsum += v   OP 2: out = v
template <int OP, int NPART>
__global__ __launch_bounds__(512, 1) void caps_reduce_kernel(
    const float* __restrict__ partial, float* __restrict__ vsum,
    float* __restrict__ out)
{
    constexpr int NPG = NPART / 16;     // partials per group (32 or 16)
    __shared__ float sd[512];
    const int bo  = blockIdx.x;         // 0..255, each block covers 32 outputs
    const int tid = threadIdx.x;
    const int kg  = tid >> 5;           // 0..15 partial-group
    const int tl  = tid & 31;           // output-within-block (coalesced)
    const int t   = bo * 32 + tl;       // global output index (= b*128+j*16+m)

    float a0 = 0.f, a1 = 0.f, a2 = 0.f, a3 = 0.f;
    float a4 = 0.f, a5 = 0.f, a6 = 0.f, a7 = 0.f;
    const float* p = partial + (size_t)kg * NPG * S_ELEMS + t;
    #pragma unroll
    for (int k = 0; k < NPG; k += 8) {
        a0 += p[(size_t)(k + 0) * S_ELEMS];
        a1 += p[(size_t)(k + 1) * S_ELEMS];
        a2 += p[(size_t)(k + 2) * S_ELEMS];
        a3 += p[(size_t)(k + 3) * S_ELEMS];
        a4 += p[(size_t)(k + 4) * S_ELEMS];
        a5 += p[(size_t)(k + 5) * S_ELEMS];
        a6 += p[(size_t)(k + 6) * S_ELEMS];
        a7 += p[(size_t)(k + 7) * S_ELEMS];
    }
    sd[tid] = ((a0 + a1) + (a2 + a3)) + ((a4 + a5) + (a6 + a7));
    __syncthreads();

    if (tid < 32) {
        float s = 0.f;
        #pragma unroll
        for (int q = 0; q < 16; ++q) s += sd[q * 32 + tid];   // bank = tid: clean
        // squash: sn over the 16 m's of this (b,j) — lanes grouped by 16
        float sn = s * s;
        sn += __shfl_xor(sn, 1);
        sn += __shfl_xor(sn, 2);
        sn += __shfl_xor(sn, 4);
        sn += __shfl_xor(sn, 8);
        const float vv = s * sqrtf(sn) / (1.f + sn);
        const int tt = bo * 32 + tid;
        if (OP == 2)      out[tt]   = vv;
        else if (OP == 1) vsum[tt] += vv;
        else              vsum[tt]  = vv;
    }
}

extern "C" void kernel_launch(void* const* d_in, const int* in_sizes, int n_in,
                              void* d_out, int out_size, void* d_ws, size_t ws_size,
                              hipStream_t stream)
{
    const float* x = (const float*)d_in[0];   // [64, 8192, 8]
    const float* W = (const float*)d_in[1];   // [8192, 8, 8, 16]
    float* out = (float*)d_out;               // [64, 8, 16]

    // 512-grid path needs (512+1)*8192 floats = 16.8 MB of workspace.
    const bool big = ws_size >= (size_t)(512 + 1) * S_ELEMS * sizeof(float);

    float* partial = (float*)d_ws;

    if (big) {
        float* vsum = partial + (size_t)512 * S_ELEMS;
        caps_pass_kernel<0, 16><<<512, 512, 0, stream>>>(x, W, vsum, partial);
        caps_reduce_kernel<0, 512><<<256, 512, 0, stream>>>(partial, vsum, nullptr);
        caps_pass_kernel<1, 16><<<512, 512, 0, stream>>>(x, W, vsum, partial);
        caps_reduce_kernel<1, 512><<<256, 512, 0, stream>>>(partial, vsum, nullptr);
        caps_pass_kernel<1, 16><<<512, 512, 0, stream>>>(x, W, vsum, partial);
        caps_reduce_kernel<2, 512><<<256, 512, 0, stream>>>(partial, vsum, out);
    } else {
        float* vsum = partial + (size_t)256 * S_ELEMS;
        caps_pass_kernel<0, 32><<<256, 512, 0, stream>>>(x, W, vsum, partial);
        caps_reduce_kernel<0, 256><<<256, 512, 0, stream>>>(partial, vsum, nullptr);
        caps_pass_kernel<1, 32><<<256, 512, 0, stream>>>(x, W, vsum, partial);
        caps_reduce_kernel<1, 256><<<256, 512, 0, stream>>>(partial, vsum, nullptr);
        caps_pass_kernel<1, 32><<<256, 512, 0, stream>>>(x, W, vsum, partial);
        caps_reduce_kernel<2, 256><<<256, 512, 0, stream>>>(partial, vsum, out);
    }
}

// Round 10
// 191.828 us; speedup vs baseline: 1.2765x; 1.0212x over previous
//
#include <hip/hip_runtime.h>

// ---------------------------------------------------------------------------
// CapsNet dynamic routing, fully fused, fp32.
//   x: [B=64, I=8192, N=8]   W: [I=8192, J=8, N=8, M=16]   out: [B, J=8, M=16]
//
// b_logits after t iters = dot(sum_{t'<=t} v_{t'}, u_hat); carry only
// vsum[B,J,M] between passes, recompute u_hat per pass (x,W are L3-resident).
//
// Round-10 single-variable experiment: IG 8 -> 4 (LDS 34,816 -> 17,408 B).
// Round 9 proved VGPR=120/no-spill and grid 512, yet occupancy stayed 18%
// (2nd block NOT co-resident). VGPR allows 4 waves/SIMD (120x4=480<=512);
// the remaining blocker hypothesis is the CDNA LDS scheduling pool = 64 KB/CU
// (160 KB is the per-workgroup max, not the schedulable budget; cf.
// sharedMemPerMultiprocessor=65536 on CDNA3). 34,816x2 = 69,632 > 65,536 ->
// refused. 17,408x2 = 34,816 <= 65,536 -> 2 blocks/CU = 16 waves/CU.
// Cost: 4 staging barriers per block instead of 2 (negligible).
//
// Body facts (do not regress):
//   * x from GLOBAL (32 KB/block chunk, L1-resident at NCH=16). x-in-LDS
//     (rounds 7/8) costs +8 VGPR -> 128 -> ~53 MB/pass scratch spill.
//   * __launch_bounds__(512,1): VGPR=120 zero-spill. 1024-thread blocks are
//     hard-capped at 64 VGPR (rounds 3-5). amdgpu_waves_per_eu and LDS
//     padding do not move the allocator.
//   * Thread = (bq, j, mq): owns b in {bq,bq+16,bq+32,bq+48}; one W
//     ds_read_b128 feeds 4b x 4m = 16 FMAs. WJ_STRIDE=136 -> 2-way banks.
//   * Softmax: m-dot via DPP quad_perm xor1/xor2 (VALU), j-denominator via
//     DPP row_ror:4/8 + one shfl_xor(16). No max-subtract (|logit| <~ 1).
// Reduce: NP=512, 256 blocks x 512 thr, 16 groups x 8-ILP; OP0 writes vsum
// (no memset dispatch).
// ---------------------------------------------------------------------------

#define BB      64
#define ICAPS   8192
#define NDIM    8
#define JCAPS   8
#define MDIM    16
#define IG      4                     // i's staged per barrier (LDS <= 32 KB!)
#define WJ_STRIDE 136                 // 136 mod 32 = 8 -> j-rows 8 banks apart
#define WI_STRIDE (JCAPS * WJ_STRIDE) // 1088 floats per i
#define S_ELEMS  (BB * JCAPS * MDIM)  // 8192 floats per s / vsum / out

// butterfly / rotate adds on the VALU pipe via DPP.
template <int CTRL>
__device__ __forceinline__ float dpp_xadd(float v) {
    const int p = __builtin_amdgcn_mov_dpp(__float_as_int(v), CTRL, 0xF, 0xF, true);
    return v + __int_as_float(p);
}
#define DPP_XOR1 0xB1   // quad_perm [1,0,3,2]
#define DPP_XOR2 0x4E   // quad_perm [2,3,0,1]
#define DPP_ROR4 0x124  // row_ror:4
#define DPP_ROR8 0x128  // row_ror:8

// MODE 0: uniform c = 1/8 (softmax of zero logits)
// MODE 1: c = softmax_j( dot(vsum[b,j,:], u_hat[b,i,j,:]) )
// NCH: i's per block (16 for the 512-grid path, 32 for the 256 fallback)
template <int MODE, int NCH>
__global__ __launch_bounds__(512, 1)
void caps_pass_kernel(
    const float* __restrict__ x, const float* __restrict__ W,
    const float* __restrict__ vsum, float* __restrict__ partial)
{
    __shared__ float Wlds[IG * WI_STRIDE];   // 17,408 B (<= 32 KB: 2 blocks/CU)

    const int tid = threadIdx.x;             // 0..511
    const int mq  = tid & 3;                 // m-quad (lane bits 0-1)
    const int j   = (tid >> 2) & 7;          // out-cap (lane bits 2-4)
    const int bq  = tid >> 5;                // 0..15 batch-quad base
    const int blk = blockIdx.x;
    const int i0  = blk * NCH;

    float s[4][4];                           // [b-quad][m-quad]
    #pragma unroll
    for (int k = 0; k < 4; ++k)
        #pragma unroll
        for (int m = 0; m < 4; ++m) s[k][m] = 0.f;

    float v[4][4];
    if (MODE == 1) {
        #pragma unroll
        for (int k = 0; k < 4; ++k) {
            const float4 a = *(const float4*)
                &vsum[((bq + 16 * k) * JCAPS + j) * MDIM + mq * 4];
            v[k][0] = a.x; v[k][1] = a.y; v[k][2] = a.z; v[k][3] = a.w;
        }
    }

    for (int st = 0; st < NCH / IG; ++st) {
        // ---- stage W for IG i's (each thread: 8 contiguous floats) ----
        {
            const int iL  = tid >> 7;        // 0..3
            const int rem = tid & 127;       // 8-float chunk within the i
            const float4* src = (const float4*)(W + (size_t)(i0 + st * IG + iL) * 1024
                                                  + rem * 8);
            float4* dst = (float4*)&Wlds[iL * WI_STRIDE + (rem >> 4) * WJ_STRIDE
                                         + (rem & 15) * 8];
            dst[0] = src[0]; dst[1] = src[1];
        }
        __syncthreads();

        #pragma unroll
        for (int ii = 0; ii < IG; ++ii) {
            const int i = i0 + st * IG + ii;

            float u[4][4];
            #pragma unroll
            for (int k = 0; k < 4; ++k)
                #pragma unroll
                for (int m = 0; m < 4; ++m) u[k][m] = 0.f;
            const float* wb = &Wlds[ii * WI_STRIDE + j * WJ_STRIDE + mq * 4];

            // n-split: keep only 16 x-floats live at a time (VGPR pressure)
            {   // n = 0..3
                float4 xa[4];
                #pragma unroll
                for (int k = 0; k < 4; ++k)
                    xa[k] = *(const float4*)&x[((size_t)(bq + 16 * k) * ICAPS + i) * NDIM];
                #pragma unroll
                for (int n = 0; n < 4; ++n) {
                    const float4 wq = *(const float4*)&wb[n * MDIM];
                    #pragma unroll
                    for (int k = 0; k < 4; ++k) {
                        const float xn = (n == 0) ? xa[k].x : (n == 1) ? xa[k].y
                                       : (n == 2) ? xa[k].z : xa[k].w;
                        u[k][0] += xn * wq.x; u[k][1] += xn * wq.y;
                        u[k][2] += xn * wq.z; u[k][3] += xn * wq.w;
                    }
                }
            }
            {   // n = 4..7
                float4 xb[4];
                #pragma unroll
                for (int k = 0; k < 4; ++k)
                    xb[k] = *(const float4*)&x[((size_t)(bq + 16 * k) * ICAPS + i) * NDIM + 4];
                #pragma unroll
                for (int n = 0; n < 4; ++n) {
                    const float4 wq = *(const float4*)&wb[(n + 4) * MDIM];
                    #pragma unroll
                    for (int k = 0; k < 4; ++k) {
                        const float xn = (n == 0) ? xb[k].x : (n == 1) ? xb[k].y
                                       : (n == 2) ? xb[k].z : xb[k].w;
                        u[k][0] += xn * wq.x; u[k][1] += xn * wq.y;
                        u[k][2] += xn * wq.z; u[k][3] += xn * wq.w;
                    }
                }
            }

            if (MODE == 0) {
                #pragma unroll
                for (int k = 0; k < 4; ++k)
                    #pragma unroll
                    for (int m = 0; m < 4; ++m) s[k][m] += u[k][m];
            } else {
                // partial logit over this m-quad (4 independent chains)
                float lp[4];
                #pragma unroll
                for (int k = 0; k < 4; ++k)
                    lp[k] = u[k][0] * v[k][0] + u[k][1] * v[k][1]
                          + u[k][2] * v[k][2] + u[k][3] * v[k][3];
                // complete m-dot across the 4 mq lanes: DPP quad_perm (VALU)
                #pragma unroll
                for (int k = 0; k < 4; ++k) lp[k] = dpp_xadd<DPP_XOR1>(lp[k]);
                #pragma unroll
                for (int k = 0; k < 4; ++k) lp[k] = dpp_xadd<DPP_XOR2>(lp[k]);
                // softmax over 8 j's: quads uniform -> row_ror:4/8 (VALU) sums
                // the 4 j's of this 16-row; one shfl_xor(16) folds the other.
                float e[4], d[4];
                #pragma unroll
                for (int k = 0; k < 4; ++k) { e[k] = __expf(lp[k]); }
                #pragma unroll
                for (int k = 0; k < 4; ++k) d[k] = dpp_xadd<DPP_ROR4>(e[k]);
                #pragma unroll
                for (int k = 0; k < 4; ++k) d[k] = dpp_xadd<DPP_ROR8>(d[k]);
                #pragma unroll
                for (int k = 0; k < 4; ++k) d[k] += __shfl_xor(d[k], 16);
                #pragma unroll
                for (int k = 0; k < 4; ++k) {
                    const float c = e[k] * __builtin_amdgcn_rcpf(d[k]);
                    #pragma unroll
                    for (int m = 0; m < 4; ++m) s[k][m] += c * u[k][m];
                }
            }
        }
        __syncthreads();
    }

    // ---- store block-partial s: partial[blk][b][j][m] (each owned once) ----
    const float sc = (MODE == 0) ? 0.125f : 1.0f;
    float* pp = partial + (size_t)blk * S_ELEMS;
    #pragma unroll
    for (int k = 0; k < 4; ++k) {
        float4 o;
        o.x = s[k][0] * sc; o.y = s[k][1] * sc;
        o.z = s[k][2] * sc; o.w = s[k][3] * sc;
        *(float4*)&pp[((bq + 16 * k) * JCAPS + j) * MDIM + mq * 4] = o;
    }
}

// Sum NPART partials -> s[b,j,m]; v = squash(s). 256 blocks x 512 threads:
// 16 groups of NPART/16 partials, 8-way ILP.
// OP 0: vsum = v (first pass, avoids memset)   OP 1: vsum += v   OP 2: out = v
template <int OP, int NPART>
__global__ __launch_bounds__(512, 1) void caps_reduce_kernel(
    const float* __restrict__ partial, float* __restrict__ vsum,
    float* __restrict__ out)
{
    constexpr int NPG = NPART / 16;     // partials per group (32 or 16)
    __shared__ float sd[512];
    const int bo  = blockIdx.x;         // 0..255, each block covers 32 outputs
    const int tid = threadIdx.x;
    const int kg  = tid >> 5;           // 0..15 partial-group
    const int tl  = tid & 31;           // output-within-block (coalesced)
    const int t   = bo * 32 + tl;       // global output index (= b*128+j*16+m)

    float a0 = 0.f, a1 = 0.f, a2 = 0.f, a3 = 0.f;
    float a4 = 0.f, a5 = 0.f, a6 = 0.f, a7 = 0.f;
    const float* p = partial + (size_t)kg * NPG * S_ELEMS + t;
    #pragma unroll
    for (int k = 0; k < NPG; k += 8) {
        a0 += p[(size_t)(k + 0) * S_ELEMS];
        a1 += p[(size_t)(k + 1) * S_ELEMS];
        a2 += p[(size_t)(k + 2) * S_ELEMS];
        a3 += p[(size_t)(k + 3) * S_ELEMS];
        a4 += p[(size_t)(k + 4) * S_ELEMS];
        a5 += p[(size_t)(k + 5) * S_ELEMS];
        a6 += p[(size_t)(k + 6) * S_ELEMS];
        a7 += p[(size_t)(k + 7) * S_ELEMS];
    }
    sd[tid] = ((a0 + a1) + (a2 + a3)) + ((a4 + a5) + (a6 + a7));
    __syncthreads();

    if (tid < 32) {
        float s = 0.f;
        #pragma unroll
        for (int q = 0; q < 16; ++q) s += sd[q * 32 + tid];   // bank = tid: clean
        // squash: sn over the 16 m's of this (b,j) — lanes grouped by 16
        float sn = s * s;
        sn += __shfl_xor(sn, 1);
        sn += __shfl_xor(sn, 2);
        sn += __shfl_xor(sn, 4);
        sn += __shfl_xor(sn, 8);
        const float vv = s * sqrtf(sn) / (1.f + sn);
        const int tt = bo * 32 + tid;
        if (OP == 2)      out[tt]   = vv;
        else if (OP == 1) vsum[tt] += vv;
        else              vsum[tt]  = vv;
    }
}

extern "C" void kernel_launch(void* const* d_in, const int* in_sizes, int n_in,
                              void* d_out, int out_size, void* d_ws, size_t ws_size,
                              hipStream_t stream)
{
    const float* x = (const float*)d_in[0];   // [64, 8192, 8]
    const float* W = (const float*)d_in[1];   // [8192, 8, 8, 16]
    float* out = (float*)d_out;               // [64, 8, 16]

    // 512-grid path needs (512+1)*8192 floats = 16.8 MB of workspace.
    const bool big = ws_size >= (size_t)(512 + 1) * S_ELEMS * sizeof(float);

    float* partial = (float*)d_ws;

    if (big) {
        float* vsum = partial + (size_t)512 * S_ELEMS;
        caps_pass_kernel<0, 16><<<512, 512, 0, stream>>>(x, W, vsum, partial);
        caps_reduce_kernel<0, 512><<<256, 512, 0, stream>>>(partial, vsum, nullptr);
        caps_pass_kernel<1, 16><<<512, 512, 0, stream>>>(x, W, vsum, partial);
        caps_reduce_kernel<1, 512><<<256, 512, 0, stream>>>(partial, vsum, nullptr);
        caps_pass_kernel<1, 16><<<512, 512, 0, stream>>>(x, W, vsum, partial);
        caps_reduce_kernel<2, 512><<<256, 512, 0, stream>>>(partial, vsum, out);
    } else {
        float* vsum = partial + (size_t)256 * S_ELEMS;
        caps_pass_kernel<0, 32><<<256, 512, 0, stream>>>(x, W, vsum, partial);
        caps_reduce_kernel<0, 256><<<256, 512, 0, stream>>>(partial, vsum, nullptr);
        caps_pass_kernel<1, 32><<<256, 512, 0, stream>>>(x, W, vsum, partial);
        caps_reduce_kernel<1, 256><<<256, 512, 0, stream>>>(partial, vsum, nullptr);
        caps_pass_kernel<1, 32><<<256, 512, 0, stream>>>(x, W, vsum, partial);
        caps_reduce_kernel<2, 256><<<256, 512, 0, stream>>>(partial, vsum, out);
    }
}